// Round 5
// baseline (920.070 us; speedup 1.0000x reference)
//
#include <hip/hip_runtime.h>
#include <hip/hip_bf16.h>

typedef unsigned short ushort_t;
typedef _Float16 h2 __attribute__((ext_vector_type(2)));
typedef _Float16 half4_t __attribute__((ext_vector_type(4)));
typedef _Float16 half8_t __attribute__((ext_vector_type(8)));
typedef float f32x4 __attribute__((ext_vector_type(4)));
#define EPSQ 1e-8f

__device__ __forceinline__ float fdot2f(h2 a, h2 b, float c) {
#if __has_builtin(__builtin_amdgcn_fdot2)
  return __builtin_amdgcn_fdot2(a, b, c, false);
#else
  return fmaf((float)a.x, (float)b.x, fmaf((float)a.y, (float)b.y, c));
#endif
}
__device__ __forceinline__ h2 bc_h2(unsigned int v) { return __builtin_bit_cast(h2, v); }
__device__ __forceinline__ unsigned int bc_u32(h2 v) { return __builtin_bit_cast(unsigned int, v); }
__device__ __forceinline__ ushort_t bc_u16(_Float16 v) { return __builtin_bit_cast(ushort_t, v); }

// ws layout (bytes):
//   wc16  [9][64][128] fp16 : off 0        size 147456   (conv1 weights, K-chunked)
//   pwB16 [64][160]    fp16 : off 147456   size 20480    (pconv weights, kk=k*48+ci)
//   Whs   [245760]     fp16 : off 167936   size 491520   (routing W, chunk-major: [(o*16+d)][c][8])
//   u16   [4096][384][8] fp16: off 659456  size 25165824
// total ~25.8 MB

// ---------------- K0: weight prep ----------------
__global__ __launch_bounds__(256) void k0_prep(
    const float* __restrict__ w1, const float* __restrict__ pw,
    const float* __restrict__ Wf,
    _Float16* __restrict__ wc16, _Float16* __restrict__ pwB16,
    _Float16* __restrict__ Whs)
{
  int i = blockIdx.x * 256 + threadIdx.x;   // grid 960*256 = 245760
  if (i < 73728) {
    int c  = i / 8192;
    int r  = i % 8192;
    int co = r >> 7;
    int k  = r & 127;
    wc16[i] = (co < 50) ? (_Float16)w1[co*1152 + k*9 + c] : (_Float16)0.f;
  }
  if (i < 10240) {
    int co2 = i / 160, kk = i % 160;
    int k = kk / 48, ci = kk % 48;
    float v = (k < 3 && ci < 42) ? pw[co2*126 + ci*3 + k] : 0.f;
    pwB16[i] = (_Float16)v;
  }
  // W permute to chunk-major: Wf idx i = ((o*384+c)*16+d)*8+i8
  // -> Whs[((o*16+d)*384+c)*8+i8]  (so k3's per-(o,d) load is lane-coalesced 16B/thread)
  {
    int i8 = i & 7;
    int r  = i >> 3;
    int d  = r & 15;
    int rc = r >> 4;
    int c  = rc % 384;
    int o  = rc / 384;
    Whs[(((o*16 + d)*384) + c)*8 + i8] = (_Float16)Wf[i];
  }
}

// ---------------- K12: MFMA conv1 + relu + MFMA pconv + squash (3 b per block) ----------------
__global__ __launch_bounds__(256) void k12_mfma(
    const float* __restrict__ x, const float* __restrict__ b1,
    const float* __restrict__ b2, const _Float16* __restrict__ wc16,
    const _Float16* __restrict__ pwB16, ushort_t* __restrict__ u16)
{
  __shared__ float smem[19728];
  _Float16* xh   = (_Float16*)smem;
  _Float16* hr16 = (_Float16*)smem;
  _Float16* pB   = (_Float16*)smem + 8736;
  float*    pbuf = smem + 9744;

  const int tid   = threadIdx.x;
  const int w     = tid >> 6;
  const int lane  = tid & 63;
  const int lc    = lane & 15;
  const int qd    = lane >> 4;
  const int gbase = blockIdx.x * 3;

  // ---- stage x: fp32 -> fp16 into padded rows ----
  for (int j = tid; j < 4800; j += 256) {
    int g = j / 1600, r = j - g*1600;
    int p = r >> 5, q = r & 31;
    int bb = gbase + g; if (bb > 4095) bb = 4095;
    float4 v = *(const float4*)(x + bb*6400 + p*128 + q*4);
    half4_t hv = {(_Float16)v.x, (_Float16)v.y, (_Float16)v.z, (_Float16)v.w};
    *(half4_t*)(xh + g*6800 + p*136 + q*4) = hv;
  }
  // ---- stage w chunk 0 into Bbuf0 ----
  {
    const uint4* wg = (const uint4*)wc16;
    uint4* dst = (uint4*)(xh + 20400);
#pragma unroll
    for (int it = 0; it < 4; ++it) {
      int f = it*256 + tid;
      dst[(f >> 4)*17 + (f & 15)] = wg[f];
    }
  }

  const _Float16* abase[2];
#pragma unroll
  for (int tm = 0; tm < 2; ++tm) {
    int m = 32*w + 16*tm + lc;
    if (m > 125) m = 125;
    int g = m / 42, l = m - g*42;
    abase[tm] = xh + g*6800 + l*136 + qd*8;
  }

  f32x4 acc[2][4];
#pragma unroll
  for (int tm = 0; tm < 2; ++tm)
#pragma unroll
    for (int tn = 0; tn < 4; ++tn)
      acc[tm][tn] = (f32x4){0.f, 0.f, 0.f, 0.f};

  __syncthreads();

  uint4 pf[4];
  for (int c = 0; c < 9; ++c) {
    if (c < 8) {
      const uint4* wg = (const uint4*)wc16 + (c + 1)*1024;
#pragma unroll
      for (int it = 0; it < 4; ++it) pf[it] = wg[it*256 + tid];
    }
    const _Float16* Bb = xh + 20400 + (c & 1)*8704;
    const _Float16* a0 = abase[0] + c*136;
    const _Float16* a1 = abase[1] + c*136;
#pragma unroll
    for (int kk = 0; kk < 128; kk += 32) {
      half8_t av0 = *(const half8_t*)(a0 + kk);
      half8_t av1 = *(const half8_t*)(a1 + kk);
#pragma unroll
      for (int tn = 0; tn < 4; ++tn) {
        half8_t bv = *(const half8_t*)(Bb + (16*tn + lc)*136 + qd*8 + kk);
        acc[0][tn] = __builtin_amdgcn_mfma_f32_16x16x32_f16(av0, bv, acc[0][tn], 0, 0, 0);
        acc[1][tn] = __builtin_amdgcn_mfma_f32_16x16x32_f16(av1, bv, acc[1][tn], 0, 0, 0);
      }
    }
    __syncthreads();
    if (c < 8) {
      uint4* dst = (uint4*)(xh + 20400 + ((c + 1) & 1)*8704);
#pragma unroll
      for (int it = 0; it < 4; ++it) {
        int f = it*256 + tid;
        dst[(f >> 4)*17 + (f & 15)] = pf[it];
      }
      __syncthreads();
    }
  }

  // ---- zero hr16 and stage pconv weights ----
  for (int j = tid; j < 4368; j += 256) smem[j] = 0.f;
  {
    const uint4* pg = (const uint4*)pwB16;
    uint4* dst = (uint4*)pB;
    for (int f = tid; f < 1280; f += 256) {
      int row = f / 20, cc = f - row*20;
      dst[row*21 + cc] = pg[f];
    }
  }
  __syncthreads();

  // ---- conv1 epilogue: bias+relu -> hr16[g][co][l] fp16 ----
#pragma unroll
  for (int tm = 0; tm < 2; ++tm) {
    int mb = 32*w + 16*tm + 4*qd;
#pragma unroll
    for (int tn = 0; tn < 4; ++tn) {
      int co = 16*tn + lc;
      if (co < 50) {
        float bias = b1[co];
#pragma unroll
        for (int r = 0; r < 4; ++r) {
          int m = mb + r;
          if (m < 126) {
            int g = m / 42, l = m - g*42;
            hr16[g*2912 + co*56 + l] = (_Float16)fmaxf(acc[tm][tn][r] + bias, 0.f);
          }
        }
      }
    }
  }
  __syncthreads();

  // ---- pconv MFMA: M=144, N=64, K=160 ----
  f32x4 acc2[3][4];
#pragma unroll
  for (int tm = 0; tm < 3; ++tm)
#pragma unroll
    for (int tn = 0; tn < 4; ++tn)
      acc2[tm][tn] = (f32x4){0.f, 0.f, 0.f, 0.f};

#pragma unroll
  for (int kc = 0; kc < 5; ++kc) {
    int kk0 = kc*32 + qd*8;
    int k   = (kk0 >= 144) ? 3 : (kk0 >= 96) ? 2 : (kk0 >= 48) ? 1 : 0;
    int ci0 = kk0 - k*48;
    half8_t bv[4];
#pragma unroll
    for (int tn = 0; tn < 4; ++tn)
      bv[tn] = *(const half8_t*)(pB + (16*tn + lc)*168 + kk0);
#pragma unroll
    for (int tm = 0; tm < 3; ++tm) {
      int T = w + 4*tm; int Tc = (T < 9) ? T : 8;
      int g = Tc/3, l2 = (Tc - g*3)*16 + lc;
      half8_t av = *(const half8_t*)(hr16 + g*2912 + (l2 + k)*56 + ci0);
#pragma unroll
      for (int tn = 0; tn < 4; ++tn)
        acc2[tm][tn] = __builtin_amdgcn_mfma_f32_16x16x32_f16(av, bv[tn], acc2[tm][tn], 0, 0, 0);
    }
  }

  // ---- pconv epilogue -> pbuf[g][co2][l2] ----
#pragma unroll
  for (int tm = 0; tm < 3; ++tm) {
    int T = w + 4*tm;
    if (T < 9) {
      int g = T/3, l2b = (T - g*3)*16;
#pragma unroll
      for (int tn = 0; tn < 4; ++tn) {
        int co2 = 16*tn + lc;
        float bias2 = b2[co2];
#pragma unroll
        for (int r = 0; r < 4; ++r) {
          int l2 = l2b + 4*qd + r;
          pbuf[g*3328 + co2*52 + l2] = acc2[tm][tn][r] + bias2;
        }
      }
    }
  }
  __syncthreads();

  // ---- squash all 3 g -> u16 (fp16) ----
  for (int idx = tid; idx < 1152; idx += 256) {
    int g = idx / 384, cap = idx - g*384;
    int bb = gbase + g;
    if (bb < 4096) {
      int co2 = cap / 6, gg = cap - co2*6;
      const float* pp = pbuf + g*3328 + co2*52 + gg*8;
      float4 a0 = *(const float4*)pp;
      float4 a1 = *(const float4*)(pp + 4);
      float sq = a0.x*a0.x + a0.y*a0.y + a0.z*a0.z + a0.w*a0.w
               + a1.x*a1.x + a1.y*a1.y + a1.z*a1.z + a1.w*a1.w;
      float sc = sq / ((1.f + sq) * (sqrtf(sq) + EPSQ));
      h2 p0 = {(_Float16)(a0.x*sc), (_Float16)(a0.y*sc)};
      h2 p1 = {(_Float16)(a0.z*sc), (_Float16)(a0.w*sc)};
      h2 p2 = {(_Float16)(a1.x*sc), (_Float16)(a1.y*sc)};
      h2 p3 = {(_Float16)(a1.z*sc), (_Float16)(a1.w*sc)};
      *(uint4*)(u16 + ((size_t)bb*384 + cap)*8) =
          make_uint4(bc_u32(p0), bc_u32(p1), bc_u32(p2), bc_u32(p3));
    }
  }
}

// ---------------- K3: u_hat + routing, register-resident, NB=3. ----------------
// R12: R4's spill root cause: with block=384 and NO min-waves bound, hipcc's
// DEFAULT register budget is 128 VGPR/wave (4 waves/EU heuristic; R4 counters:
// VGPR=128 + 372MB WRITE_SIZE scratch). NB=3 needs ~200. Fix: explicit
// __launch_bounds__(384, 1) -> 512 VGPR cap. Completes the R2 lesson: a large
// register-resident working set needs a correctly-SIZED bound - neither too
// tight (R2: 4 -> 64 VGPR, spill) nor absent (R4: default 128, spill).
// Verify via WRITE_SIZE ~ 1.3MB; if still >10MB, fall back to NB=2.
__global__ __launch_bounds__(384, 1) void k3_route(
    const ushort_t* __restrict__ u16, const _Float16* __restrict__ Whs,
    float* __restrict__ out)
{
  __shared__ __align__(16) float part[3][6][80];
  __shared__ __align__(16) ushort_t svh16[3][80];

  const int t    = threadIdx.x;
  const int b0   = blockIdx.x * 3;       // grid 1366
  const int w    = t >> 6;
  const int lane = t & 63;
  // bitrev4 of lane&15: which j this lane holds after the halving butterfly
  const int jmap = ((lane & 1) << 3) | ((lane & 2) << 1) | ((lane & 4) >> 1) | ((lane & 8) >> 3);

  // load u (fp16) for 3 batches; thread t owns capsule c = t
  h2 ua[3][4];
#pragma unroll
  for (int bb = 0; bb < 3; ++bb) {
    int bidx = b0 + bb; if (bidx > 4095) bidx = 4095;
    uint4 uu = *(const uint4*)(u16 + ((size_t)bidx*384 + t)*8);
    ua[bb][0] = bc_h2(uu.x); ua[bb][1] = bc_h2(uu.y);
    ua[bb][2] = bc_h2(uu.z); ua[bb][3] = bc_h2(uu.w);
  }

  // ---- W-phase: u_hat into registers only; each W load pair feeds 3 batches ----
  h2 uhreg[3][40];
  const uint4* wb = (const uint4*)Whs;
#pragma unroll
  for (int o = 0; o < 5; ++o) {
    const uint4* wp = wb + (size_t)(o*16)*384 + t;
#pragma unroll
    for (int dd = 0; dd < 8; ++dd) {
      uint4 w0 = wp[(size_t)(2*dd)*384];
      uint4 w1 = wp[(size_t)(2*dd + 1)*384];
#pragma unroll
      for (int bb = 0; bb < 3; ++bb) {
        float s00 = fdot2f(bc_h2(w0.x), ua[bb][0], fdot2f(bc_h2(w0.y), ua[bb][1],
                    fdot2f(bc_h2(w0.z), ua[bb][2], fdot2f(bc_h2(w0.w), ua[bb][3], 0.f))));
        float s10 = fdot2f(bc_h2(w1.x), ua[bb][0], fdot2f(bc_h2(w1.y), ua[bb][1],
                    fdot2f(bc_h2(w1.z), ua[bb][2], fdot2f(bc_h2(w1.w), ua[bb][3], 0.f))));
        uhreg[bb][o*8 + dd] = (h2){(_Float16)s00, (_Float16)s10};
      }
    }
  }

  float lg[3][5] = {{0,0,0,0,0},{0,0,0,0,0},{0,0,0,0,0}};

  const bool s0 = (lane & 1) != 0;
  const bool s1 = (lane & 2) != 0;
  const bool s2 = (lane & 4) != 0;
  const bool s3 = (lane & 8) != 0;

  for (int it = 0; it < 3; ++it) {
    // softmax over o (thread-local, fp32 coef) + butterfly per (bb, o)
#pragma unroll
    for (int bb = 0; bb < 3; ++bb) {
      float co[5];
      {
        float m = fmaxf(fmaxf(fmaxf(lg[bb][0],lg[bb][1]),fmaxf(lg[bb][2],lg[bb][3])),lg[bb][4]);
        float Z = 0.f;
#pragma unroll
        for (int o = 0; o < 5; ++o) { co[o] = __expf(lg[bb][o]-m); Z += co[o]; }
        float inv = 1.f / Z;
#pragma unroll
        for (int o = 0; o < 5; ++o) co[o] *= inv;
      }

      // s-phase: multi-value halving butterfly per o.
#pragma unroll
      for (int o = 0; o < 5; ++o) {
        float v16[16];
#pragma unroll
        for (int dd = 0; dd < 8; ++dd) {
          h2 uh = uhreg[bb][o*8 + dd];
          v16[2*dd]     = co[o] * (float)uh.x;
          v16[2*dd + 1] = co[o] * (float)uh.y;
        }
        float v8[8];
#pragma unroll
        for (int i = 0; i < 8; ++i) {
          float keep = s0 ? v16[i+8] : v16[i];
          float send = s0 ? v16[i]   : v16[i+8];
          v8[i] = keep + __shfl_xor(send, 1);
        }
        float v4[4];
#pragma unroll
        for (int i = 0; i < 4; ++i) {
          float keep = s1 ? v8[i+4] : v8[i];
          float send = s1 ? v8[i]   : v8[i+4];
          v4[i] = keep + __shfl_xor(send, 2);
        }
        float v2[2];
#pragma unroll
        for (int i = 0; i < 2; ++i) {
          float keep = s2 ? v4[i+2] : v4[i];
          float send = s2 ? v4[i]   : v4[i+2];
          v2[i] = keep + __shfl_xor(send, 4);
        }
        float v1;
        {
          float keep = s3 ? v2[1] : v2[0];
          float send = s3 ? v2[0] : v2[1];
          v1 = keep + __shfl_xor(send, 8);
        }
        v1 += __shfl_xor(v1, 16);
        v1 += __shfl_xor(v1, 32);
        if (lane < 16) part[bb][w][o*16 + jmap] = v1;
      }
    }
    __syncthreads();

    // stage-2: t<240 combines the 6 wave partials, squashes, broadcasts v
    if (t < 240) {
      int bb = t / 80, idx = t - bb*80;
      float s = part[bb][0][idx] + part[bb][1][idx] + part[bb][2][idx]
              + part[bb][3][idx] + part[bb][4][idx] + part[bb][5][idx];
      float sq = s * s;
      sq += __shfl_xor(sq, 1);
      sq += __shfl_xor(sq, 2);
      sq += __shfl_xor(sq, 4);
      sq += __shfl_xor(sq, 8);   // sum over the 16 d of this o (16-aligned groups)
      float f = sq / ((1.f + sq) * (sqrtf(sq) + EPSQ));
      if (it == 2) {
        if (b0 + bb < 4096) out[(size_t)(b0 + bb)*80 + idx] = s * f;
      } else {
        svh16[bb][idx] = bc_u16((_Float16)(s * f));
      }
    }
    __syncthreads();

    if (it < 2) {
      // logits update: dv = <tu, v> via packed fdot2 from registers + svh16
#pragma unroll
      for (int bb = 0; bb < 3; ++bb) {
#pragma unroll
        for (int o = 0; o < 5; ++o) {
          uint4 sa = *(const uint4*)&svh16[bb][o*16];
          uint4 sb = *(const uint4*)&svh16[bb][o*16 + 8];
          float dv = 0.f;
          dv = fdot2f(uhreg[bb][o*8+0], bc_h2(sa.x), dv);
          dv = fdot2f(uhreg[bb][o*8+1], bc_h2(sa.y), dv);
          dv = fdot2f(uhreg[bb][o*8+2], bc_h2(sa.z), dv);
          dv = fdot2f(uhreg[bb][o*8+3], bc_h2(sa.w), dv);
          dv = fdot2f(uhreg[bb][o*8+4], bc_h2(sb.x), dv);
          dv = fdot2f(uhreg[bb][o*8+5], bc_h2(sb.y), dv);
          dv = fdot2f(uhreg[bb][o*8+6], bc_h2(sb.z), dv);
          dv = fdot2f(uhreg[bb][o*8+7], bc_h2(sb.w), dv);
          lg[bb][o] += dv;
        }
      }
    }
  }
}

extern "C" void kernel_launch(void* const* d_in, const int* in_sizes, int n_in,
                              void* d_out, int out_size, void* d_ws, size_t ws_size,
                              hipStream_t stream) {
  const float* x  = (const float*)d_in[0];
  const float* w1 = (const float*)d_in[1];
  const float* b1 = (const float*)d_in[2];
  const float* pw = (const float*)d_in[3];
  const float* b2 = (const float*)d_in[4];
  const float* Wf = (const float*)d_in[5];
  float* out = (float*)d_out;
  char* ws = (char*)d_ws;

  _Float16* wc16  = (_Float16*)(ws);
  _Float16* pwB16 = (_Float16*)(ws + 147456);
  _Float16* Whs   = (_Float16*)(ws + 167936);
  ushort_t* u16   = (ushort_t*)(ws + 659456);

  k0_prep<<<960, 256, 0, stream>>>(w1, pw, Wf, wc16, pwB16, Whs);
  k12_mfma<<<1366, 256, 0, stream>>>(x, b1, b2, wc16, pwB16, u16);
  k3_route<<<1366, 384, 0, stream>>>(u16, Whs, out);
}

// Round 6
// 516.147 us; speedup vs baseline: 1.7826x; 1.7826x over previous
//
#include <hip/hip_runtime.h>
#include <hip/hip_bf16.h>

typedef unsigned short ushort_t;
typedef _Float16 h2 __attribute__((ext_vector_type(2)));
typedef _Float16 half4_t __attribute__((ext_vector_type(4)));
typedef _Float16 half8_t __attribute__((ext_vector_type(8)));
typedef float f32x4 __attribute__((ext_vector_type(4)));
#define EPSQ 1e-8f

#if __has_attribute(amdgpu_waves_per_eu)
#define K3_WAVES_HINT __attribute__((amdgpu_waves_per_eu(1, 2)))
#else
#define K3_WAVES_HINT
#endif

__device__ __forceinline__ float fdot2f(h2 a, h2 b, float c) {
#if __has_builtin(__builtin_amdgcn_fdot2)
  return __builtin_amdgcn_fdot2(a, b, c, false);
#else
  return fmaf((float)a.x, (float)b.x, fmaf((float)a.y, (float)b.y, c));
#endif
}
__device__ __forceinline__ h2 bc_h2(unsigned int v) { return __builtin_bit_cast(h2, v); }
__device__ __forceinline__ unsigned int bc_u32(h2 v) { return __builtin_bit_cast(unsigned int, v); }
__device__ __forceinline__ ushort_t bc_u16(_Float16 v) { return __builtin_bit_cast(ushort_t, v); }

// ws layout (bytes):
//   wc16  [9][64][128] fp16 : off 0        size 147456   (conv1 weights, K-chunked)
//   pwB16 [64][160]    fp16 : off 147456   size 20480    (pconv weights, kk=k*48+ci)
//   Whs   [245760]     fp16 : off 167936   size 491520   (routing W, chunk-major: [(o*16+d)][c][8])
//   u16   [4096][384][8] fp16: off 659456  size 25165824
// total ~25.8 MB

// ---------------- K0: weight prep ----------------
__global__ __launch_bounds__(256) void k0_prep(
    const float* __restrict__ w1, const float* __restrict__ pw,
    const float* __restrict__ Wf,
    _Float16* __restrict__ wc16, _Float16* __restrict__ pwB16,
    _Float16* __restrict__ Whs)
{
  int i = blockIdx.x * 256 + threadIdx.x;   // grid 960*256 = 245760
  if (i < 73728) {
    int c  = i / 8192;
    int r  = i % 8192;
    int co = r >> 7;
    int k  = r & 127;
    wc16[i] = (co < 50) ? (_Float16)w1[co*1152 + k*9 + c] : (_Float16)0.f;
  }
  if (i < 10240) {
    int co2 = i / 160, kk = i % 160;
    int k = kk / 48, ci = kk % 48;
    float v = (k < 3 && ci < 42) ? pw[co2*126 + ci*3 + k] : 0.f;
    pwB16[i] = (_Float16)v;
  }
  // W permute to chunk-major: Wf idx i = ((o*384+c)*16+d)*8+i8
  // -> Whs[((o*16+d)*384+c)*8+i8]  (so k3's per-(o,d) load is lane-coalesced 16B/thread)
  {
    int i8 = i & 7;
    int r  = i >> 3;
    int d  = r & 15;
    int rc = r >> 4;
    int c  = rc % 384;
    int o  = rc / 384;
    Whs[(((o*16 + d)*384) + c)*8 + i8] = (_Float16)Wf[i];
  }
}

// ---------------- K12: MFMA conv1 + relu + MFMA pconv + squash (3 b per block) ----------------
__global__ __launch_bounds__(256) void k12_mfma(
    const float* __restrict__ x, const float* __restrict__ b1,
    const float* __restrict__ b2, const _Float16* __restrict__ wc16,
    const _Float16* __restrict__ pwB16, ushort_t* __restrict__ u16)
{
  __shared__ float smem[19728];
  _Float16* xh   = (_Float16*)smem;
  _Float16* hr16 = (_Float16*)smem;
  _Float16* pB   = (_Float16*)smem + 8736;
  float*    pbuf = smem + 9744;

  const int tid   = threadIdx.x;
  const int w     = tid >> 6;
  const int lane  = tid & 63;
  const int lc    = lane & 15;
  const int qd    = lane >> 4;
  const int gbase = blockIdx.x * 3;

  // ---- stage x: fp32 -> fp16 into padded rows ----
  for (int j = tid; j < 4800; j += 256) {
    int g = j / 1600, r = j - g*1600;
    int p = r >> 5, q = r & 31;
    int bb = gbase + g; if (bb > 4095) bb = 4095;
    float4 v = *(const float4*)(x + bb*6400 + p*128 + q*4);
    half4_t hv = {(_Float16)v.x, (_Float16)v.y, (_Float16)v.z, (_Float16)v.w};
    *(half4_t*)(xh + g*6800 + p*136 + q*4) = hv;
  }
  // ---- stage w chunk 0 into Bbuf0 ----
  {
    const uint4* wg = (const uint4*)wc16;
    uint4* dst = (uint4*)(xh + 20400);
#pragma unroll
    for (int it = 0; it < 4; ++it) {
      int f = it*256 + tid;
      dst[(f >> 4)*17 + (f & 15)] = wg[f];
    }
  }

  const _Float16* abase[2];
#pragma unroll
  for (int tm = 0; tm < 2; ++tm) {
    int m = 32*w + 16*tm + lc;
    if (m > 125) m = 125;
    int g = m / 42, l = m - g*42;
    abase[tm] = xh + g*6800 + l*136 + qd*8;
  }

  f32x4 acc[2][4];
#pragma unroll
  for (int tm = 0; tm < 2; ++tm)
#pragma unroll
    for (int tn = 0; tn < 4; ++tn)
      acc[tm][tn] = (f32x4){0.f, 0.f, 0.f, 0.f};

  __syncthreads();

  uint4 pf[4];
  for (int c = 0; c < 9; ++c) {
    if (c < 8) {
      const uint4* wg = (const uint4*)wc16 + (c + 1)*1024;
#pragma unroll
      for (int it = 0; it < 4; ++it) pf[it] = wg[it*256 + tid];
    }
    const _Float16* Bb = xh + 20400 + (c & 1)*8704;
    const _Float16* a0 = abase[0] + c*136;
    const _Float16* a1 = abase[1] + c*136;
#pragma unroll
    for (int kk = 0; kk < 128; kk += 32) {
      half8_t av0 = *(const half8_t*)(a0 + kk);
      half8_t av1 = *(const half8_t*)(a1 + kk);
#pragma unroll
      for (int tn = 0; tn < 4; ++tn) {
        half8_t bv = *(const half8_t*)(Bb + (16*tn + lc)*136 + qd*8 + kk);
        acc[0][tn] = __builtin_amdgcn_mfma_f32_16x16x32_f16(av0, bv, acc[0][tn], 0, 0, 0);
        acc[1][tn] = __builtin_amdgcn_mfma_f32_16x16x32_f16(av1, bv, acc[1][tn], 0, 0, 0);
      }
    }
    __syncthreads();
    if (c < 8) {
      uint4* dst = (uint4*)(xh + 20400 + ((c + 1) & 1)*8704);
#pragma unroll
      for (int it = 0; it < 4; ++it) {
        int f = it*256 + tid;
        dst[(f >> 4)*17 + (f & 15)] = pf[it];
      }
      __syncthreads();
    }
  }

  // ---- zero hr16 and stage pconv weights ----
  for (int j = tid; j < 4368; j += 256) smem[j] = 0.f;
  {
    const uint4* pg = (const uint4*)pwB16;
    uint4* dst = (uint4*)pB;
    for (int f = tid; f < 1280; f += 256) {
      int row = f / 20, cc = f - row*20;
      dst[row*21 + cc] = pg[f];
    }
  }
  __syncthreads();

  // ---- conv1 epilogue: bias+relu -> hr16[g][co][l] fp16 ----
#pragma unroll
  for (int tm = 0; tm < 2; ++tm) {
    int mb = 32*w + 16*tm + 4*qd;
#pragma unroll
    for (int tn = 0; tn < 4; ++tn) {
      int co = 16*tn + lc;
      if (co < 50) {
        float bias = b1[co];
#pragma unroll
        for (int r = 0; r < 4; ++r) {
          int m = mb + r;
          if (m < 126) {
            int g = m / 42, l = m - g*42;
            hr16[g*2912 + co*56 + l] = (_Float16)fmaxf(acc[tm][tn][r] + bias, 0.f);
          }
        }
      }
    }
  }
  __syncthreads();

  // ---- pconv MFMA: M=144, N=64, K=160 ----
  f32x4 acc2[3][4];
#pragma unroll
  for (int tm = 0; tm < 3; ++tm)
#pragma unroll
    for (int tn = 0; tn < 4; ++tn)
      acc2[tm][tn] = (f32x4){0.f, 0.f, 0.f, 0.f};

#pragma unroll
  for (int kc = 0; kc < 5; ++kc) {
    int kk0 = kc*32 + qd*8;
    int k   = (kk0 >= 144) ? 3 : (kk0 >= 96) ? 2 : (kk0 >= 48) ? 1 : 0;
    int ci0 = kk0 - k*48;
    half8_t bv[4];
#pragma unroll
    for (int tn = 0; tn < 4; ++tn)
      bv[tn] = *(const half8_t*)(pB + (16*tn + lc)*168 + kk0);
#pragma unroll
    for (int tm = 0; tm < 3; ++tm) {
      int T = w + 4*tm; int Tc = (T < 9) ? T : 8;
      int g = Tc/3, l2 = (Tc - g*3)*16 + lc;
      half8_t av = *(const half8_t*)(hr16 + g*2912 + (l2 + k)*56 + ci0);
#pragma unroll
      for (int tn = 0; tn < 4; ++tn)
        acc2[tm][tn] = __builtin_amdgcn_mfma_f32_16x16x32_f16(av, bv[tn], acc2[tm][tn], 0, 0, 0);
    }
  }

  // ---- pconv epilogue -> pbuf[g][co2][l2] ----
#pragma unroll
  for (int tm = 0; tm < 3; ++tm) {
    int T = w + 4*tm;
    if (T < 9) {
      int g = T/3, l2b = (T - g*3)*16;
#pragma unroll
      for (int tn = 0; tn < 4; ++tn) {
        int co2 = 16*tn + lc;
        float bias2 = b2[co2];
#pragma unroll
        for (int r = 0; r < 4; ++r) {
          int l2 = l2b + 4*qd + r;
          pbuf[g*3328 + co2*52 + l2] = acc2[tm][tn][r] + bias2;
        }
      }
    }
  }
  __syncthreads();

  // ---- squash all 3 g -> u16 (fp16) ----
  for (int idx = tid; idx < 1152; idx += 256) {
    int g = idx / 384, cap = idx - g*384;
    int bb = gbase + g;
    if (bb < 4096) {
      int co2 = cap / 6, gg = cap - co2*6;
      const float* pp = pbuf + g*3328 + co2*52 + gg*8;
      float4 a0 = *(const float4*)pp;
      float4 a1 = *(const float4*)(pp + 4);
      float sq = a0.x*a0.x + a0.y*a0.y + a0.z*a0.z + a0.w*a0.w
               + a1.x*a1.x + a1.y*a1.y + a1.z*a1.z + a1.w*a1.w;
      float sc = sq / ((1.f + sq) * (sqrtf(sq) + EPSQ));
      h2 p0 = {(_Float16)(a0.x*sc), (_Float16)(a0.y*sc)};
      h2 p1 = {(_Float16)(a0.z*sc), (_Float16)(a0.w*sc)};
      h2 p2 = {(_Float16)(a1.x*sc), (_Float16)(a1.y*sc)};
      h2 p3 = {(_Float16)(a1.z*sc), (_Float16)(a1.w*sc)};
      *(uint4*)(u16 + ((size_t)bb*384 + cap)*8) =
          make_uint4(bc_u32(p0), bc_u32(p1), bc_u32(p2), bc_u32(p3));
    }
  }
}

// ---------------- K3: u_hat + routing, register-resident, NB=2. ----------------
// R13 ledger: R4/R5 proved hipcc's default VGPR budget for a 384-thread block
// is 128 and __launch_bounds__(384,1) does NOT raise it (identical codegen).
// So: make NB=2 fit UNDER 128 by construction: uhreg[2][40]=80 regs + non-uhreg
// overhead 52 (measured R3: 92 total at uhreg=40), minus 8 by splitting the
// s-phase butterfly into two 8-value groups (temps 16->8) => peak ~124.
// amdgpu_waves_per_eu(1,2) attribute (256-VGPR budget) as insurance if the
// estimate is off. Spill tripwire: WRITE_SIZE >> 2MB.
__global__ __launch_bounds__(384) K3_WAVES_HINT void k3_route(
    const ushort_t* __restrict__ u16, const _Float16* __restrict__ Whs,
    float* __restrict__ out)
{
  __shared__ __align__(16) float part[2][6][80];
  __shared__ __align__(16) ushort_t svh16[2][80];

  const int t    = threadIdx.x;
  const int b0   = blockIdx.x * 2;       // grid 2048 (exact)
  const int w    = t >> 6;
  const int lane = t & 63;
  // bitrev3 of lane&7: which j (within an 8-group) this lane holds after the
  // 8-value halving butterfly
  const int jmap3 = ((lane & 1) << 2) | (lane & 2) | ((lane & 4) >> 2);

  // load u (fp16) for 2 batches; thread t owns capsule c = t
  h2 ua[2][4];
#pragma unroll
  for (int bb = 0; bb < 2; ++bb) {
    uint4 uu = *(const uint4*)(u16 + ((size_t)(b0 + bb)*384 + t)*8);
    ua[bb][0] = bc_h2(uu.x); ua[bb][1] = bc_h2(uu.y);
    ua[bb][2] = bc_h2(uu.z); ua[bb][3] = bc_h2(uu.w);
  }

  // ---- W-phase: u_hat into registers only; each W load pair feeds 2 batches ----
  h2 uhreg[2][40];
  const uint4* wb = (const uint4*)Whs;
#pragma unroll
  for (int o = 0; o < 5; ++o) {
    const uint4* wp = wb + (size_t)(o*16)*384 + t;
#pragma unroll
    for (int dd = 0; dd < 8; ++dd) {
      uint4 w0 = wp[(size_t)(2*dd)*384];
      uint4 w1 = wp[(size_t)(2*dd + 1)*384];
#pragma unroll
      for (int bb = 0; bb < 2; ++bb) {
        float s00 = fdot2f(bc_h2(w0.x), ua[bb][0], fdot2f(bc_h2(w0.y), ua[bb][1],
                    fdot2f(bc_h2(w0.z), ua[bb][2], fdot2f(bc_h2(w0.w), ua[bb][3], 0.f))));
        float s10 = fdot2f(bc_h2(w1.x), ua[bb][0], fdot2f(bc_h2(w1.y), ua[bb][1],
                    fdot2f(bc_h2(w1.z), ua[bb][2], fdot2f(bc_h2(w1.w), ua[bb][3], 0.f))));
        uhreg[bb][o*8 + dd] = (h2){(_Float16)s00, (_Float16)s10};
      }
    }
  }

  float lg[2][5] = {{0,0,0,0,0},{0,0,0,0,0}};

  const bool s0 = (lane & 1) != 0;
  const bool s1 = (lane & 2) != 0;
  const bool s2 = (lane & 4) != 0;

  for (int it = 0; it < 3; ++it) {
    // softmax over o (thread-local, fp32 coef) + butterflies per (bb, o)
#pragma unroll
    for (int bb = 0; bb < 2; ++bb) {
      float co[5];
      {
        float m = fmaxf(fmaxf(fmaxf(lg[bb][0],lg[bb][1]),fmaxf(lg[bb][2],lg[bb][3])),lg[bb][4]);
        float Z = 0.f;
#pragma unroll
        for (int o = 0; o < 5; ++o) { co[o] = __expf(lg[bb][o]-m); Z += co[o]; }
        float inv = 1.f / Z;
#pragma unroll
        for (int o = 0; o < 5; ++o) co[o] *= inv;
      }

      // s-phase: two 8-value halving butterflies per o (temps 8, not 16)
#pragma unroll
      for (int o = 0; o < 5; ++o) {
#pragma unroll
        for (int g = 0; g < 2; ++g) {
          float p[8];
#pragma unroll
          for (int m2 = 0; m2 < 4; ++m2) {
            h2 uh = uhreg[bb][o*8 + g*4 + m2];
            p[2*m2]     = co[o] * (float)uh.x;   // d = 8g + 2m2
            p[2*m2 + 1] = co[o] * (float)uh.y;   // d = 8g + 2m2 + 1
          }
          float v4[4];
#pragma unroll
          for (int i = 0; i < 4; ++i) {
            float keep = s0 ? p[i+4] : p[i];
            float send = s0 ? p[i]   : p[i+4];
            v4[i] = keep + __shfl_xor(send, 1);
          }
          float v2[2];
#pragma unroll
          for (int i = 0; i < 2; ++i) {
            float keep = s1 ? v4[i+2] : v4[i];
            float send = s1 ? v4[i]   : v4[i+2];
            v2[i] = keep + __shfl_xor(send, 2);
          }
          float v1;
          {
            float keep = s2 ? v2[1] : v2[0];
            float send = s2 ? v2[0] : v2[1];
            v1 = keep + __shfl_xor(send, 4);
          }
          v1 += __shfl_xor(v1, 8);
          v1 += __shfl_xor(v1, 16);
          v1 += __shfl_xor(v1, 32);
          if (lane < 8) part[bb][w][o*16 + g*8 + jmap3] = v1;
        }
      }
    }
    __syncthreads();

    // stage-2: t<160 combines the 6 wave partials, squashes, broadcasts v
    if (t < 160) {
      int bb = t >> 7 ? 1 : (t >= 80 ? 1 : 0);   // t/80
      int idx = t - bb*80;
      float s = part[bb][0][idx] + part[bb][1][idx] + part[bb][2][idx]
              + part[bb][3][idx] + part[bb][4][idx] + part[bb][5][idx];
      float sq = s * s;
      sq += __shfl_xor(sq, 1);
      sq += __shfl_xor(sq, 2);
      sq += __shfl_xor(sq, 4);
      sq += __shfl_xor(sq, 8);   // sum over the 16 d of this o (16-aligned groups)
      float f = sq / ((1.f + sq) * (sqrtf(sq) + EPSQ));
      if (it == 2) out[(size_t)(b0 + bb)*80 + idx] = s * f;
      else         svh16[bb][idx] = bc_u16((_Float16)(s * f));
    }
    __syncthreads();

    if (it < 2) {
      // logits update: dv = <tu, v> via packed fdot2 from registers + svh16
#pragma unroll
      for (int bb = 0; bb < 2; ++bb) {
#pragma unroll
        for (int o = 0; o < 5; ++o) {
          uint4 sa = *(const uint4*)&svh16[bb][o*16];
          uint4 sb = *(const uint4*)&svh16[bb][o*16 + 8];
          float dv = 0.f;
          dv = fdot2f(uhreg[bb][o*8+0], bc_h2(sa.x), dv);
          dv = fdot2f(uhreg[bb][o*8+1], bc_h2(sa.y), dv);
          dv = fdot2f(uhreg[bb][o*8+2], bc_h2(sa.z), dv);
          dv = fdot2f(uhreg[bb][o*8+3], bc_h2(sa.w), dv);
          dv = fdot2f(uhreg[bb][o*8+4], bc_h2(sb.x), dv);
          dv = fdot2f(uhreg[bb][o*8+5], bc_h2(sb.y), dv);
          dv = fdot2f(uhreg[bb][o*8+6], bc_h2(sb.z), dv);
          dv = fdot2f(uhreg[bb][o*8+7], bc_h2(sb.w), dv);
          lg[bb][o] += dv;
        }
      }
    }
  }
}

extern "C" void kernel_launch(void* const* d_in, const int* in_sizes, int n_in,
                              void* d_out, int out_size, void* d_ws, size_t ws_size,
                              hipStream_t stream) {
  const float* x  = (const float*)d_in[0];
  const float* w1 = (const float*)d_in[1];
  const float* b1 = (const float*)d_in[2];
  const float* pw = (const float*)d_in[3];
  const float* b2 = (const float*)d_in[4];
  const float* Wf = (const float*)d_in[5];
  float* out = (float*)d_out;
  char* ws = (char*)d_ws;

  _Float16* wc16  = (_Float16*)(ws);
  _Float16* pwB16 = (_Float16*)(ws + 147456);
  _Float16* Whs   = (_Float16*)(ws + 167936);
  ushort_t* u16   = (ushort_t*)(ws + 659456);

  k0_prep<<<960, 256, 0, stream>>>(w1, pw, Wf, wc16, pwB16, Whs);
  k12_mfma<<<1366, 256, 0, stream>>>(x, b1, b2, wc16, pwB16, u16);
  k3_route<<<2048, 384, 0, stream>>>(u16, Whs, out);
}

// Round 7
// 466.883 us; speedup vs baseline: 1.9707x; 1.1055x over previous
//
#include <hip/hip_runtime.h>
#include <hip/hip_bf16.h>

typedef unsigned short ushort_t;
typedef _Float16 h2 __attribute__((ext_vector_type(2)));
typedef _Float16 half4_t __attribute__((ext_vector_type(4)));
typedef _Float16 half8_t __attribute__((ext_vector_type(8)));
typedef float f32x4 __attribute__((ext_vector_type(4)));
#define EPSQ 1e-8f

__device__ __forceinline__ float fdot2f(h2 a, h2 b, float c) {
#if __has_builtin(__builtin_amdgcn_fdot2)
  return __builtin_amdgcn_fdot2(a, b, c, false);
#else
  return fmaf((float)a.x, (float)b.x, fmaf((float)a.y, (float)b.y, c));
#endif
}
__device__ __forceinline__ h2 bc_h2(unsigned int v) { return __builtin_bit_cast(h2, v); }
__device__ __forceinline__ unsigned int bc_u32(h2 v) { return __builtin_bit_cast(unsigned int, v); }
__device__ __forceinline__ ushort_t bc_u16(_Float16 v) { return __builtin_bit_cast(ushort_t, v); }

// ws layout (bytes):
//   wc16  [9][64][128] fp16 : off 0        size 147456   (conv1 weights, K-chunked)
//   pwB16 [64][160]    fp16 : off 147456   size 20480    (pconv weights, kk=k*48+ci)
//   Whs   [245760]     fp16 : off 167936   size 491520   (routing W, chunk-major: [(o*16+d)][c][8])
//   u16   [4096][384][8] fp16: off 659456  size 25165824
// total ~25.8 MB

// ---------------- K0: weight prep ----------------
__global__ __launch_bounds__(256) void k0_prep(
    const float* __restrict__ w1, const float* __restrict__ pw,
    const float* __restrict__ Wf,
    _Float16* __restrict__ wc16, _Float16* __restrict__ pwB16,
    _Float16* __restrict__ Whs)
{
  int i = blockIdx.x * 256 + threadIdx.x;   // grid 960*256 = 245760
  if (i < 73728) {
    int c  = i / 8192;
    int r  = i % 8192;
    int co = r >> 7;
    int k  = r & 127;
    wc16[i] = (co < 50) ? (_Float16)w1[co*1152 + k*9 + c] : (_Float16)0.f;
  }
  if (i < 10240) {
    int co2 = i / 160, kk = i % 160;
    int k = kk / 48, ci = kk % 48;
    float v = (k < 3 && ci < 42) ? pw[co2*126 + ci*3 + k] : 0.f;
    pwB16[i] = (_Float16)v;
  }
  // W permute to chunk-major: Wf idx i = ((o*384+c)*16+d)*8+i8
  // -> Whs[((o*16+d)*384+c)*8+i8]  (so k3's per-(o,d) load is lane-coalesced 16B/thread)
  {
    int i8 = i & 7;
    int r  = i >> 3;
    int d  = r & 15;
    int rc = r >> 4;
    int c  = rc % 384;
    int o  = rc / 384;
    Whs[(((o*16 + d)*384) + c)*8 + i8] = (_Float16)Wf[i];
  }
}

// ---------------- K12: MFMA conv1 + relu + MFMA pconv + squash (3 b per block) ----------------
__global__ __launch_bounds__(256) void k12_mfma(
    const float* __restrict__ x, const float* __restrict__ b1,
    const float* __restrict__ b2, const _Float16* __restrict__ wc16,
    const _Float16* __restrict__ pwB16, ushort_t* __restrict__ u16)
{
  __shared__ float smem[19728];
  _Float16* xh   = (_Float16*)smem;
  _Float16* hr16 = (_Float16*)smem;
  _Float16* pB   = (_Float16*)smem + 8736;
  float*    pbuf = smem + 9744;

  const int tid   = threadIdx.x;
  const int w     = tid >> 6;
  const int lane  = tid & 63;
  const int lc    = lane & 15;
  const int qd    = lane >> 4;
  const int gbase = blockIdx.x * 3;

  // ---- stage x: fp32 -> fp16 into padded rows ----
  for (int j = tid; j < 4800; j += 256) {
    int g = j / 1600, r = j - g*1600;
    int p = r >> 5, q = r & 31;
    int bb = gbase + g; if (bb > 4095) bb = 4095;
    float4 v = *(const float4*)(x + bb*6400 + p*128 + q*4);
    half4_t hv = {(_Float16)v.x, (_Float16)v.y, (_Float16)v.z, (_Float16)v.w};
    *(half4_t*)(xh + g*6800 + p*136 + q*4) = hv;
  }
  // ---- stage w chunk 0 into Bbuf0 ----
  {
    const uint4* wg = (const uint4*)wc16;
    uint4* dst = (uint4*)(xh + 20400);
#pragma unroll
    for (int it = 0; it < 4; ++it) {
      int f = it*256 + tid;
      dst[(f >> 4)*17 + (f & 15)] = wg[f];
    }
  }

  const _Float16* abase[2];
#pragma unroll
  for (int tm = 0; tm < 2; ++tm) {
    int m = 32*w + 16*tm + lc;
    if (m > 125) m = 125;
    int g = m / 42, l = m - g*42;
    abase[tm] = xh + g*6800 + l*136 + qd*8;
  }

  f32x4 acc[2][4];
#pragma unroll
  for (int tm = 0; tm < 2; ++tm)
#pragma unroll
    for (int tn = 0; tn < 4; ++tn)
      acc[tm][tn] = (f32x4){0.f, 0.f, 0.f, 0.f};

  __syncthreads();

  uint4 pf[4];
  for (int c = 0; c < 9; ++c) {
    if (c < 8) {
      const uint4* wg = (const uint4*)wc16 + (c + 1)*1024;
#pragma unroll
      for (int it = 0; it < 4; ++it) pf[it] = wg[it*256 + tid];
    }
    const _Float16* Bb = xh + 20400 + (c & 1)*8704;
    const _Float16* a0 = abase[0] + c*136;
    const _Float16* a1 = abase[1] + c*136;
#pragma unroll
    for (int kk = 0; kk < 128; kk += 32) {
      half8_t av0 = *(const half8_t*)(a0 + kk);
      half8_t av1 = *(const half8_t*)(a1 + kk);
#pragma unroll
      for (int tn = 0; tn < 4; ++tn) {
        half8_t bv = *(const half8_t*)(Bb + (16*tn + lc)*136 + qd*8 + kk);
        acc[0][tn] = __builtin_amdgcn_mfma_f32_16x16x32_f16(av0, bv, acc[0][tn], 0, 0, 0);
        acc[1][tn] = __builtin_amdgcn_mfma_f32_16x16x32_f16(av1, bv, acc[1][tn], 0, 0, 0);
      }
    }
    __syncthreads();
    if (c < 8) {
      uint4* dst = (uint4*)(xh + 20400 + ((c + 1) & 1)*8704);
#pragma unroll
      for (int it = 0; it < 4; ++it) {
        int f = it*256 + tid;
        dst[(f >> 4)*17 + (f & 15)] = pf[it];
      }
      __syncthreads();
    }
  }

  // ---- zero hr16 and stage pconv weights ----
  for (int j = tid; j < 4368; j += 256) smem[j] = 0.f;
  {
    const uint4* pg = (const uint4*)pwB16;
    uint4* dst = (uint4*)pB;
    for (int f = tid; f < 1280; f += 256) {
      int row = f / 20, cc = f - row*20;
      dst[row*21 + cc] = pg[f];
    }
  }
  __syncthreads();

  // ---- conv1 epilogue: bias+relu -> hr16[g][co][l] fp16 ----
#pragma unroll
  for (int tm = 0; tm < 2; ++tm) {
    int mb = 32*w + 16*tm + 4*qd;
#pragma unroll
    for (int tn = 0; tn < 4; ++tn) {
      int co = 16*tn + lc;
      if (co < 50) {
        float bias = b1[co];
#pragma unroll
        for (int r = 0; r < 4; ++r) {
          int m = mb + r;
          if (m < 126) {
            int g = m / 42, l = m - g*42;
            hr16[g*2912 + co*56 + l] = (_Float16)fmaxf(acc[tm][tn][r] + bias, 0.f);
          }
        }
      }
    }
  }
  __syncthreads();

  // ---- pconv MFMA: M=144, N=64, K=160 ----
  f32x4 acc2[3][4];
#pragma unroll
  for (int tm = 0; tm < 3; ++tm)
#pragma unroll
    for (int tn = 0; tn < 4; ++tn)
      acc2[tm][tn] = (f32x4){0.f, 0.f, 0.f, 0.f};

#pragma unroll
  for (int kc = 0; kc < 5; ++kc) {
    int kk0 = kc*32 + qd*8;
    int k   = (kk0 >= 144) ? 3 : (kk0 >= 96) ? 2 : (kk0 >= 48) ? 1 : 0;
    int ci0 = kk0 - k*48;
    half8_t bv[4];
#pragma unroll
    for (int tn = 0; tn < 4; ++tn)
      bv[tn] = *(const half8_t*)(pB + (16*tn + lc)*168 + kk0);
#pragma unroll
    for (int tm = 0; tm < 3; ++tm) {
      int T = w + 4*tm; int Tc = (T < 9) ? T : 8;
      int g = Tc/3, l2 = (Tc - g*3)*16 + lc;
      half8_t av = *(const half8_t*)(hr16 + g*2912 + (l2 + k)*56 + ci0);
#pragma unroll
      for (int tn = 0; tn < 4; ++tn)
        acc2[tm][tn] = __builtin_amdgcn_mfma_f32_16x16x32_f16(av, bv[tn], acc2[tm][tn], 0, 0, 0);
    }
  }

  // ---- pconv epilogue -> pbuf[g][co2][l2] ----
#pragma unroll
  for (int tm = 0; tm < 3; ++tm) {
    int T = w + 4*tm;
    if (T < 9) {
      int g = T/3, l2b = (T - g*3)*16;
#pragma unroll
      for (int tn = 0; tn < 4; ++tn) {
        int co2 = 16*tn + lc;
        float bias2 = b2[co2];
#pragma unroll
        for (int r = 0; r < 4; ++r) {
          int l2 = l2b + 4*qd + r;
          pbuf[g*3328 + co2*52 + l2] = acc2[tm][tn][r] + bias2;
        }
      }
    }
  }
  __syncthreads();

  // ---- squash all 3 g -> u16 (fp16) ----
  for (int idx = tid; idx < 1152; idx += 256) {
    int g = idx / 384, cap = idx - g*384;
    int bb = gbase + g;
    if (bb < 4096) {
      int co2 = cap / 6, gg = cap - co2*6;
      const float* pp = pbuf + g*3328 + co2*52 + gg*8;
      float4 a0 = *(const float4*)pp;
      float4 a1 = *(const float4*)(pp + 4);
      float sq = a0.x*a0.x + a0.y*a0.y + a0.z*a0.z + a0.w*a0.w
               + a1.x*a1.x + a1.y*a1.y + a1.z*a1.z + a1.w*a1.w;
      float sc = sq / ((1.f + sq) * (sqrtf(sq) + EPSQ));
      h2 p0 = {(_Float16)(a0.x*sc), (_Float16)(a0.y*sc)};
      h2 p1 = {(_Float16)(a0.z*sc), (_Float16)(a0.w*sc)};
      h2 p2 = {(_Float16)(a1.x*sc), (_Float16)(a1.y*sc)};
      h2 p3 = {(_Float16)(a1.z*sc), (_Float16)(a1.w*sc)};
      *(uint4*)(u16 + ((size_t)bb*384 + cap)*8) =
          make_uint4(bc_u32(p0), bc_u32(p1), bc_u32(p2), bc_u32(p3));
    }
  }
}

// ---------------- K3: u_hat + routing, NB=2: b0 in regs, b1 in LDS-private. ----------------
// R14 ledger: 384-thread blocks have an immovable 128-VGPR cap on this hipcc
// (R4/R5: launch_bounds(,1) no-op; R6: amdgpu_waves_per_eu(1,2) no-op; both
// pinned VGPR=128 with scratch spill). NB=2-in-registers needs ~145 -> can't fit.
// Fix: spill ON PURPOSE to LDS. b1's u_hat is THREAD-PRIVATE (thread t owns
// capsule c=t), so uhb[384][82] fp16 rows need NO barriers; row stride 41
// dwords (gcd(41,32)=1) -> 4-byte accesses conflict-free, t/t+32 2-way = free.
// b0 stays in uhreg[40] (R3-proven 92-VGPR shape). W loads amortized 2x,
// rounds 16->8. Spill tripwire: WRITE_SIZE >> 2MB.
__global__ __launch_bounds__(384) void k3_route(
    const ushort_t* __restrict__ u16, const _Float16* __restrict__ Whs,
    float* __restrict__ out)
{
  __shared__ __align__(16) ushort_t uhb[384][82];   // b1 u_hat, thread-private rows
  __shared__ __align__(16) float part[2][6][80];
  __shared__ __align__(16) ushort_t svh16[2][80];

  const int t    = threadIdx.x;
  const int b0   = blockIdx.x * 2;       // grid 2048 (exact)
  const int w    = t >> 6;
  const int lane = t & 63;
  // bitrev3 of lane&7: which j (within an 8-group) this lane holds after the
  // 8-value halving butterfly
  const int jmap3 = ((lane & 1) << 2) | (lane & 2) | ((lane & 4) >> 2);

  // load u (fp16) for 2 batches; thread t owns capsule c = t
  h2 ua[2][4];
#pragma unroll
  for (int bb = 0; bb < 2; ++bb) {
    uint4 uu = *(const uint4*)(u16 + ((size_t)(b0 + bb)*384 + t)*8);
    ua[bb][0] = bc_h2(uu.x); ua[bb][1] = bc_h2(uu.y);
    ua[bb][2] = bc_h2(uu.z); ua[bb][3] = bc_h2(uu.w);
  }

  // ---- W-phase: u_hat; b0 -> registers, b1 -> LDS private row ----
  h2 uhreg[40];
  const uint4* wb = (const uint4*)Whs;
#pragma unroll
  for (int o = 0; o < 5; ++o) {
    const uint4* wp = wb + (size_t)(o*16)*384 + t;
#pragma unroll
    for (int dd = 0; dd < 8; ++dd) {
      uint4 w0 = wp[(size_t)(2*dd)*384];
      uint4 w1 = wp[(size_t)(2*dd + 1)*384];
      float s00 = fdot2f(bc_h2(w0.x), ua[0][0], fdot2f(bc_h2(w0.y), ua[0][1],
                  fdot2f(bc_h2(w0.z), ua[0][2], fdot2f(bc_h2(w0.w), ua[0][3], 0.f))));
      float s10 = fdot2f(bc_h2(w1.x), ua[0][0], fdot2f(bc_h2(w1.y), ua[0][1],
                  fdot2f(bc_h2(w1.z), ua[0][2], fdot2f(bc_h2(w1.w), ua[0][3], 0.f))));
      uhreg[o*8 + dd] = (h2){(_Float16)s00, (_Float16)s10};
      float s01 = fdot2f(bc_h2(w0.x), ua[1][0], fdot2f(bc_h2(w0.y), ua[1][1],
                  fdot2f(bc_h2(w0.z), ua[1][2], fdot2f(bc_h2(w0.w), ua[1][3], 0.f))));
      float s11 = fdot2f(bc_h2(w1.x), ua[1][0], fdot2f(bc_h2(w1.y), ua[1][1],
                  fdot2f(bc_h2(w1.z), ua[1][2], fdot2f(bc_h2(w1.w), ua[1][3], 0.f))));
      *(h2*)&uhb[t][o*16 + 2*dd] = (h2){(_Float16)s01, (_Float16)s11};
    }
  }
  // no barrier: uhb rows are thread-private

  float lg[2][5] = {{0,0,0,0,0},{0,0,0,0,0}};

  const bool s0 = (lane & 1) != 0;
  const bool s1 = (lane & 2) != 0;
  const bool s2 = (lane & 4) != 0;

  for (int it = 0; it < 3; ++it) {
    // softmax over o (thread-local, fp32 coef)
    float cof[2][5];
#pragma unroll
    for (int bb = 0; bb < 2; ++bb) {
      float m = fmaxf(fmaxf(fmaxf(lg[bb][0],lg[bb][1]),fmaxf(lg[bb][2],lg[bb][3])),lg[bb][4]);
      float Z = 0.f;
#pragma unroll
      for (int o = 0; o < 5; ++o) { cof[bb][o] = __expf(lg[bb][o]-m); Z += cof[bb][o]; }
      float inv = 1.f / Z;
#pragma unroll
      for (int o = 0; o < 5; ++o) cof[bb][o] *= inv;
    }

    // s-phase: two 8-value halving butterflies per (bb, o)
#pragma unroll
    for (int bb = 0; bb < 2; ++bb) {
#pragma unroll
      for (int o = 0; o < 5; ++o) {
#pragma unroll
        for (int g = 0; g < 2; ++g) {
          float p[8];
#pragma unroll
          for (int m2 = 0; m2 < 4; ++m2) {
            h2 uh = (bb == 0) ? uhreg[o*8 + g*4 + m2]
                              : *(const h2*)&uhb[t][o*16 + g*8 + 2*m2];
            p[2*m2]     = cof[bb][o] * (float)uh.x;   // d = 8g + 2m2
            p[2*m2 + 1] = cof[bb][o] * (float)uh.y;   // d = 8g + 2m2 + 1
          }
          float v4[4];
#pragma unroll
          for (int i = 0; i < 4; ++i) {
            float keep = s0 ? p[i+4] : p[i];
            float send = s0 ? p[i]   : p[i+4];
            v4[i] = keep + __shfl_xor(send, 1);
          }
          float v2[2];
#pragma unroll
          for (int i = 0; i < 2; ++i) {
            float keep = s1 ? v4[i+2] : v4[i];
            float send = s1 ? v4[i]   : v4[i+2];
            v2[i] = keep + __shfl_xor(send, 2);
          }
          float v1;
          {
            float keep = s2 ? v2[1] : v2[0];
            float send = s2 ? v2[0] : v2[1];
            v1 = keep + __shfl_xor(send, 4);
          }
          v1 += __shfl_xor(v1, 8);
          v1 += __shfl_xor(v1, 16);
          v1 += __shfl_xor(v1, 32);
          if (lane < 8) part[bb][w][o*16 + g*8 + jmap3] = v1;
        }
      }
    }
    __syncthreads();

    // stage-2: t<160 combines the 6 wave partials, squashes, broadcasts v
    if (t < 160) {
      int bb  = (t >= 80) ? 1 : 0;
      int idx = t - bb*80;
      float s = part[bb][0][idx] + part[bb][1][idx] + part[bb][2][idx]
              + part[bb][3][idx] + part[bb][4][idx] + part[bb][5][idx];
      float sq = s * s;
      sq += __shfl_xor(sq, 1);
      sq += __shfl_xor(sq, 2);
      sq += __shfl_xor(sq, 4);
      sq += __shfl_xor(sq, 8);   // sum over the 16 d of this o (16-aligned groups)
      float f = sq / ((1.f + sq) * (sqrtf(sq) + EPSQ));
      if (it == 2) out[(size_t)(b0 + bb)*80 + idx] = s * f;
      else         svh16[bb][idx] = bc_u16((_Float16)(s * f));
    }
    __syncthreads();

    if (it < 2) {
      // logits update: dv = <tu, v>; b0 from uhreg, b1 from uhb
#pragma unroll
      for (int bb = 0; bb < 2; ++bb) {
#pragma unroll
        for (int o = 0; o < 5; ++o) {
          uint4 sa = *(const uint4*)&svh16[bb][o*16];
          uint4 sb = *(const uint4*)&svh16[bb][o*16 + 8];
          h2 svp[8] = {bc_h2(sa.x), bc_h2(sa.y), bc_h2(sa.z), bc_h2(sa.w),
                       bc_h2(sb.x), bc_h2(sb.y), bc_h2(sb.z), bc_h2(sb.w)};
          float dv = 0.f;
#pragma unroll
          for (int k = 0; k < 8; ++k) {
            h2 uh = (bb == 0) ? uhreg[o*8 + k]
                              : *(const h2*)&uhb[t][o*16 + 2*k];
            dv = fdot2f(uh, svp[k], dv);
          }
          lg[bb][o] += dv;
        }
      }
    }
  }
}

extern "C" void kernel_launch(void* const* d_in, const int* in_sizes, int n_in,
                              void* d_out, int out_size, void* d_ws, size_t ws_size,
                              hipStream_t stream) {
  const float* x  = (const float*)d_in[0];
  const float* w1 = (const float*)d_in[1];
  const float* b1 = (const float*)d_in[2];
  const float* pw = (const float*)d_in[3];
  const float* b2 = (const float*)d_in[4];
  const float* Wf = (const float*)d_in[5];
  float* out = (float*)d_out;
  char* ws = (char*)d_ws;

  _Float16* wc16  = (_Float16*)(ws);
  _Float16* pwB16 = (_Float16*)(ws + 147456);
  _Float16* Whs   = (_Float16*)(ws + 167936);
  ushort_t* u16   = (ushort_t*)(ws + 659456);

  k0_prep<<<960, 256, 0, stream>>>(w1, pw, Wf, wc16, pwB16, Whs);
  k12_mfma<<<1366, 256, 0, stream>>>(x, b1, b2, wc16, pwB16, u16);
  k3_route<<<2048, 384, 0, stream>>>(u16, Whs, out);
}